// Round 1
// baseline (252.111 us; speedup 1.0000x reference)
//
#include <hip/hip_runtime.h>

// GraphConv: out = sum_a att[a] * (adj_a @ (X@W + b))
// N=8192, A=3, D_IN=256, D_OUT=64. All inputs fp32; output fp32.
// Strategy: stacked-K GEMM  C[8192,64] = [adj0|adj1|adj2] @ [att0*S; att1*S; att2*S]
// with S = X@W+b precomputed in bf16, packed in MFMA-B-fragment order.

#define NNODES 8192
#define DIN    256
#define DOUT   64
#define NA     3
#define KT_PER_A (NNODES / 32)   // 256 k-tiles of 32 per adjacency

typedef float f32x4 __attribute__((ext_vector_type(4)));
typedef short s16x8 __attribute__((ext_vector_type(8)));

__device__ __forceinline__ unsigned short f2bf(float f) {
    unsigned int u = __builtin_bit_cast(unsigned int, f);
    u += 0x7fffu + ((u >> 16) & 1u);      // round-to-nearest-even
    return (unsigned short)(u >> 16);
}

// ---------------------------------------------------------------------------
// Kernel 1: S[m][d] = sum_k X[m][k]*W[k][d] + b[d]; write att[a]*S in packed
// bf16 B-fragment layout:  tile (a,kt,nt) holds B[k_local][col] with
// k_local = (lane>>4)*8 + j, col = lane&15; flat = tile*512 + lane*8 + j.
// ---------------------------------------------------------------------------
__global__ __launch_bounds__(256) void prep_support(
    const float* __restrict__ x, const float* __restrict__ w,
    const float* __restrict__ bias, const float* __restrict__ att,
    unsigned short* __restrict__ Bp)
{
    const int t = threadIdx.x;
    const int d = t & 63;
    const int m = (blockIdx.x << 2) + (t >> 6);

    const float* xr = x + (size_t)m * DIN;
    float acc = bias[d];
#pragma unroll 4
    for (int k = 0; k < DIN; k += 4) {
        f32x4 xv = *(const f32x4*)(xr + k);
        acc += xv[0] * w[(k + 0) * DOUT + d];
        acc += xv[1] * w[(k + 1) * DOUT + d];
        acc += xv[2] * w[(k + 2) * DOUT + d];
        acc += xv[3] * w[(k + 3) * DOUT + d];
    }

    const int kt   = m >> 5;
    const int kl   = m & 31;
    const int lane = ((kl >> 3) << 4) | (d & 15);
    const int j    = kl & 7;
    const int nt   = d >> 4;

    const size_t base    = (size_t)(kt * 4 + nt) * 512 + lane * 8 + j;
    const size_t aStride = (size_t)KT_PER_A * 4 * 512;   // 524288 elems per adjacency

    const float a0 = att[0], a1 = att[1], a2 = att[2];
    Bp[base]               = f2bf(a0 * acc);
    Bp[base + aStride]     = f2bf(a1 * acc);
    Bp[base + 2 * aStride] = f2bf(a2 * acc);
}

// ---------------------------------------------------------------------------
// Kernel 2: one block = 16 output rows; 4 waves split K (3*8192) into quarters.
// Per k-step: A-frag from adj (fp32 -> bf16 in regs), 4 packed B-frags,
// 4x mfma_f32_16x16x32_bf16. Cross-wave reduce via LDS.
// ---------------------------------------------------------------------------
__global__ __launch_bounds__(256, 2) void graphconv_gemm(
    const float* __restrict__ adj, const unsigned short* __restrict__ Bp,
    float* __restrict__ out)
{
    const int tid  = threadIdx.x;
    const int wave = tid >> 6;
    const int lane = tid & 63;
    const int r    = lane & 15;   // A row within tile / B col
    const int g    = lane >> 4;   // k-subgroup (8 consecutive k's)
    const int n0   = blockIdx.x << 4;

    const s16x8* __restrict__ Bv = (const s16x8*)Bp;

    f32x4 acc0 = {0.f, 0.f, 0.f, 0.f};
    f32x4 acc1 = {0.f, 0.f, 0.f, 0.f};
    f32x4 acc2 = {0.f, 0.f, 0.f, 0.f};
    f32x4 acc3 = {0.f, 0.f, 0.f, 0.f};

    for (int a = 0; a < NA; ++a) {
        // per-lane A pointer: row n0+r, k base = wave's kt range + g*8
        const float* Ap = adj + (size_t)a * NNODES * NNODES
                              + (size_t)(n0 + r) * NNODES
                              + (wave << 6) * 32 + (g << 3);
        // B fragment pointer for (a, kt = wave*64, nt=0), this lane
        const s16x8* bp = Bv + ((size_t)(a * KT_PER_A + (wave << 6)) * 4) * 64 + lane;

#pragma unroll 4
        for (int t = 0; t < 64; ++t) {
            f32x4 av0 = *(const f32x4*)(Ap);
            f32x4 av1 = *(const f32x4*)(Ap + 4);
            s16x8 af;
            af[0] = (short)f2bf(av0[0]);
            af[1] = (short)f2bf(av0[1]);
            af[2] = (short)f2bf(av0[2]);
            af[3] = (short)f2bf(av0[3]);
            af[4] = (short)f2bf(av1[0]);
            af[5] = (short)f2bf(av1[1]);
            af[6] = (short)f2bf(av1[2]);
            af[7] = (short)f2bf(av1[3]);

            s16x8 b0 = bp[0];
            s16x8 b1 = bp[64];
            s16x8 b2 = bp[128];
            s16x8 b3 = bp[192];

            acc0 = __builtin_amdgcn_mfma_f32_16x16x32_bf16(af, b0, acc0, 0, 0, 0);
            acc1 = __builtin_amdgcn_mfma_f32_16x16x32_bf16(af, b1, acc1, 0, 0, 0);
            acc2 = __builtin_amdgcn_mfma_f32_16x16x32_bf16(af, b2, acc2, 0, 0, 0);
            acc3 = __builtin_amdgcn_mfma_f32_16x16x32_bf16(af, b3, acc3, 0, 0, 0);

            Ap += 32;
            bp += 256;
        }
    }

    // C/D layout (m89-verified): col = lane&15, row = (lane>>4)*4 + reg
    __shared__ float red[4][16][DOUT];
#pragma unroll
    for (int j = 0; j < 4; ++j) {
        const int row = (g << 2) + j;
        red[wave][row][r]      = acc0[j];
        red[wave][row][16 + r] = acc1[j];
        red[wave][row][32 + r] = acc2[j];
        red[wave][row][48 + r] = acc3[j];
    }
    __syncthreads();

    const float* r0 = &red[0][0][0];
    float* outt = out + (size_t)n0 * DOUT;
#pragma unroll
    for (int q = 0; q < 4; ++q) {
        const int i = (q << 8) + tid;   // 0..1023 over the 16x64 tile
        outt[i] = r0[i] + r0[1024 + i] + r0[2048 + i] + r0[3072 + i];
    }
}

// ---------------------------------------------------------------------------
extern "C" void kernel_launch(void* const* d_in, const int* in_sizes, int n_in,
                              void* d_out, int out_size, void* d_ws, size_t ws_size,
                              hipStream_t stream) {
    const float* x   = (const float*)d_in[0];   // [8192, 256]
    const float* adj = (const float*)d_in[1];   // [3, 8192, 8192]
    const float* att = (const float*)d_in[2];   // [3]
    const float* w   = (const float*)d_in[3];   // [256, 64]
    const float* b   = (const float*)d_in[4];   // [64]
    float* out = (float*)d_out;                 // [8192, 64] fp32
    unsigned short* Bp = (unsigned short*)d_ws; // 3 MB packed bf16 B operand

    prep_support<<<NNODES / 4, 256, 0, stream>>>(x, w, b, att, Bp);
    graphconv_gemm<<<NNODES / 16, 256, 0, stream>>>(adj, Bp, out);
}